// Round 1
// baseline (1045.049 us; speedup 1.0000x reference)
//
#include <hip/hip_runtime.h>
#include <math.h>

// ---------------------------------------------------------------------------
// GCN 3-layer forward: GCNConv->BN->ReLU ×2, GCNConv->log_softmax
// N=100000 nodes, E=1.6M edges, D=128 hidden, 40 classes, all fp32.
// Strategy: build CSR-by-dst once (counts -> scan -> scatter with edge coef
// dinv[s]*ew*dinv[d]); gather-based aggregation (no feature atomics); fp32
// LDS-tiled GEMM with fused BN+ReLU on the input load.
// ---------------------------------------------------------------------------

// ---------- edge-index dtype detection (int32 vs int64 layout) ----------
__global__ void k_detect(const unsigned* __restrict__ raw, int nsample, int* __restrict__ flag) {
    int i = blockIdx.x * blockDim.x + threadIdx.x;
    if (i < nsample) {
        // if data is int64 little-endian with values < 2^31, every odd word is 0
        if (raw[2 * i + 1] != 0u) atomicOr(flag, 1);
    }
}

__device__ __forceinline__ int edge_src(const unsigned* raw, int e, int E, int is64) {
    return is64 ? (int)raw[2 * (size_t)e] : (int)raw[e];
}
__device__ __forceinline__ int edge_dst(const unsigned* raw, int e, int E, int is64) {
    return is64 ? (int)raw[2 * ((size_t)E + e)] : (int)raw[(size_t)E + e];
}

// ---------- degree + per-dst edge counts ----------
__global__ void k_deg(const unsigned* __restrict__ raw, const float* __restrict__ ew,
                      float* __restrict__ degw, int* __restrict__ counts,
                      const int* __restrict__ flag, int E) {
    int e = blockIdx.x * blockDim.x + threadIdx.x;
    if (e >= E) return;
    int is64 = (*flag == 0);
    int d = edge_dst(raw, e, E, is64);
    atomicAdd(&degw[d], ew[e]);
    atomicAdd(&counts[d], 1);
}

// ---------- hierarchical exclusive scan over counts (N <= 131072) ----------
__global__ void k_scan_a(int* __restrict__ data, int* __restrict__ bsums, int N) {
    __shared__ int s[512];
    int tid = threadIdx.x;
    int i = blockIdx.x * 512 + tid;
    int v = (i < N) ? data[i] : 0;
    s[tid] = v;
    __syncthreads();
    for (int off = 1; off < 512; off <<= 1) {
        int t = (tid >= off) ? s[tid - off] : 0;
        __syncthreads();
        if (tid >= off) s[tid] += t;
        __syncthreads();
    }
    if (tid == 511) bsums[blockIdx.x] = s[511];
    if (i < N) data[i] = s[tid] - v;  // exclusive within block
}

__global__ void k_scan_b(int* __restrict__ bsums, int NB) {
    __shared__ int s[256];
    int tid = threadIdx.x;
    int v = (tid < NB) ? bsums[tid] : 0;
    s[tid] = v;
    __syncthreads();
    for (int off = 1; off < 256; off <<= 1) {
        int t = (tid >= off) ? s[tid - off] : 0;
        __syncthreads();
        if (tid >= off) s[tid] += t;
        __syncthreads();
    }
    if (tid < NB) bsums[tid] = s[tid] - v;  // exclusive block offsets
}

__global__ void k_scan_c(const int* __restrict__ data, const int* __restrict__ bsums,
                         int* __restrict__ rowptr, int* __restrict__ fill,
                         const float* __restrict__ degw, float* __restrict__ dinv,
                         int N, int E) {
    int i = blockIdx.x * 512 + threadIdx.x;
    if (i < N) {
        int v = data[i] + bsums[blockIdx.x];
        rowptr[i] = v;
        fill[i] = v;
        dinv[i] = rsqrtf(degw[i] + 1.0f);  // deg includes self-loop weight 1.0
    }
    if (blockIdx.x == 0 && threadIdx.x == 0) rowptr[N] = E;
}

// ---------- scatter edges into CSR slots with precomputed coefficient ----------
__global__ void k_scatter(const unsigned* __restrict__ raw, const float* __restrict__ ew,
                          const float* __restrict__ dinv, int* __restrict__ fill,
                          int* __restrict__ srcs, float* __restrict__ coefs,
                          const int* __restrict__ flag, int E) {
    int e = blockIdx.x * blockDim.x + threadIdx.x;
    if (e >= E) return;
    int is64 = (*flag == 0);
    int s = edge_src(raw, e, E, is64);
    int d = edge_dst(raw, e, E, is64);
    float c = dinv[s] * ew[e] * dinv[d];
    int p = atomicAdd(&fill[d], 1);
    srcs[p] = s;
    coefs[p] = c;
}

// ---------- fp32 GEMM: Y[N,DOUT] = act(X)[N,128] @ W[128,DOUT] ----------
// BN=true applies y = relu(x*scale[k]+shift[k]) to the input while staging.
// W staged in LDS in K-chunks of KC rows (keeps static LDS < 64KB).
template <int DOUT, int KC, bool BN>
__global__ __launch_bounds__(256) void k_gemm(
    const float* __restrict__ X, const float* __restrict__ W,
    const float* __restrict__ scale, const float* __restrict__ shift,
    float* __restrict__ Y, int N)
{
    constexpr int NCH = 128 / KC;
    constexpr int NC = (DOUT > 64) ? 2 : 1;
    __shared__ __align__(16) float Wl[KC * DOUT];
    __shared__ __align__(16) float Xs[4][8 * 128];
    __shared__ float sc_l[128], sh_l[128];

    const int tid = threadIdx.x;
    const int wave = tid >> 6, lane = tid & 63;
    if (BN) {
        if (tid < 128) { sc_l[tid] = scale[tid]; sh_l[tid] = shift[tid]; }
    }
    __syncthreads();

    const int srow = lane >> 3;         // 0..7 : which of the wave's 8 rows
    const int skk = (lane & 7) * 16;    // k-window start for staging
    const int cl0 = (DOUT > 64) ? lane : (lane < DOUT ? lane : 0);

    for (int base = blockIdx.x * 32; base < N; base += gridDim.x * 32) {
        // stage 8 rows per wave into wave-private LDS (no barrier needed)
        {
            int r = base + wave * 8 + srow;
            float4 v[4];
            if (r < N) {
                const float4* p = (const float4*)(X + (size_t)r * 128 + skk);
                v[0] = p[0]; v[1] = p[1]; v[2] = p[2]; v[3] = p[3];
            } else {
                v[0] = v[1] = v[2] = v[3] = make_float4(0.f, 0.f, 0.f, 0.f);
            }
            if (BN) {
                float* vf = (float*)v;
#pragma unroll
                for (int j = 0; j < 16; j++)
                    vf[j] = fmaxf(vf[j] * sc_l[skk + j] + sh_l[skk + j], 0.f);
            }
            float4* q = (float4*)&Xs[wave][srow * 128 + skk];
            q[0] = v[0]; q[1] = v[1]; q[2] = v[2]; q[3] = v[3];
        }

        float acc[8][NC];
#pragma unroll
        for (int r = 0; r < 8; r++)
#pragma unroll
            for (int c = 0; c < NC; c++) acc[r][c] = 0.f;

        for (int ch = 0; ch < NCH; ++ch) {
            __syncthreads();  // all waves done with previous Wl contents
            for (int idx = tid; idx < KC * DOUT / 4; idx += 256)
                ((float4*)Wl)[idx] = ((const float4*)(W + (size_t)ch * KC * DOUT))[idx];
            __syncthreads();

            for (int k = 0; k < KC; k += 4) {
                float4 a[8];
#pragma unroll
                for (int r = 0; r < 8; r++)
                    a[r] = *(const float4*)&Xs[wave][r * 128 + ch * KC + k];
#pragma unroll
                for (int kk = 0; kk < 4; kk++) {
                    float w0 = Wl[(k + kk) * DOUT + cl0];
                    float w1 = (NC == 2) ? Wl[(k + kk) * DOUT + 64 + lane] : 0.f;
#pragma unroll
                    for (int r = 0; r < 8; r++) {
                        float av = ((const float*)&a[r])[kk];
                        acc[r][0] += av * w0;
                        if (NC == 2) acc[r][1] += av * w1;
                    }
                }
            }
        }

#pragma unroll
        for (int r = 0; r < 8; r++) {
            int row = base + wave * 8 + r;
            if (row < N) {
                if (NC == 2) {
                    Y[(size_t)row * DOUT + lane] = acc[r][0];
                    Y[(size_t)row * DOUT + 64 + lane] = acc[r][1];
                } else if (lane < DOUT) {
                    Y[(size_t)row * DOUT + lane] = acc[r][0];
                }
            }
        }
    }
}

// ---------- aggregation (128-wide) + bias + BN partial sums ----------
__global__ __launch_bounds__(128) void k_agg128(
    const float* __restrict__ xw, const int* __restrict__ rowptr,
    const int* __restrict__ srcs, const float* __restrict__ coefs,
    const float* __restrict__ dinv, const float* __restrict__ bias,
    float* __restrict__ h, float* __restrict__ bn_sum, float* __restrict__ bn_sq,
    int N)
{
    const int f = threadIdx.x;  // feature 0..127
    const int base = blockIdx.x * 64;
    const float b = bias[f];
    float ssum = 0.f, ssq = 0.f;
    const int nmax = min(64, N - base);
    for (int n = 0; n < nmax; n++) {
        const int i = base + n;
        const int rs = rowptr[i], re = rowptr[i + 1];
        const float di = dinv[i];
        float acc = di * di * xw[(size_t)i * 128 + f];  // self-loop message
        int j = rs;
        for (; j + 4 <= re; j += 4) {
            int s0 = srcs[j], s1 = srcs[j + 1], s2 = srcs[j + 2], s3 = srcs[j + 3];
            float c0 = coefs[j], c1 = coefs[j + 1], c2 = coefs[j + 2], c3 = coefs[j + 3];
            float v0 = xw[(size_t)s0 * 128 + f];
            float v1 = xw[(size_t)s1 * 128 + f];
            float v2 = xw[(size_t)s2 * 128 + f];
            float v3 = xw[(size_t)s3 * 128 + f];
            acc += c0 * v0 + c1 * v1 + c2 * v2 + c3 * v3;
        }
        for (; j < re; j++) acc += coefs[j] * xw[(size_t)srcs[j] * 128 + f];
        acc += b;
        h[(size_t)i * 128 + f] = acc;
        ssum += acc;
        ssq += acc * acc;
    }
    atomicAdd(&bn_sum[f], ssum);
    atomicAdd(&bn_sq[f], ssq);
}

// ---------- BN finalize: scale/shift for y = x*scale+shift ----------
__global__ void k_bnfin(const float* __restrict__ bn_sum, const float* __restrict__ bn_sq,
                        const float* __restrict__ gamma, const float* __restrict__ beta,
                        float* __restrict__ scale, float* __restrict__ shift, int N) {
    int f = threadIdx.x;
    float inv = 1.0f / (float)N;
    float m = bn_sum[f] * inv;
    float v = bn_sq[f] * inv - m * m;  // biased variance (torch BN normalization)
    float sc = gamma[f] * rsqrtf(v + 1e-5f);
    scale[f] = sc;
    shift[f] = beta[f] - m * sc;
}

// ---------- aggregation (40-wide) + bias + log_softmax -> d_out ----------
__global__ __launch_bounds__(256) void k_agg40(
    const float* __restrict__ xw, const int* __restrict__ rowptr,
    const int* __restrict__ srcs, const float* __restrict__ coefs,
    const float* __restrict__ dinv, const float* __restrict__ bias,
    float* __restrict__ out, int N)
{
    const int gtid = blockIdx.x * blockDim.x + threadIdx.x;
    const int wid = gtid >> 6;
    const int lane = threadIdx.x & 63;
    const int nw = (gridDim.x * blockDim.x) >> 6;
    const bool act = lane < 40;
    const float b = act ? bias[lane] : 0.f;
    for (int i = wid; i < N; i += nw) {
        const int rs = rowptr[i], re = rowptr[i + 1];
        const float di = dinv[i];
        float acc = act ? di * di * xw[(size_t)i * 40 + lane] : 0.f;
        int j = rs;
        for (; j + 2 <= re; j += 2) {
            int s0 = srcs[j], s1 = srcs[j + 1];
            float c0 = coefs[j], c1 = coefs[j + 1];
            if (act) acc += c0 * xw[(size_t)s0 * 40 + lane] + c1 * xw[(size_t)s1 * 40 + lane];
        }
        for (; j < re; j++) {
            if (act) acc += coefs[j] * xw[(size_t)srcs[j] * 40 + lane];
        }
        acc += b;
        float m = act ? acc : -1e30f;
#pragma unroll
        for (int off = 32; off; off >>= 1) m = fmaxf(m, __shfl_xor(m, off));
        float ex = act ? expf(acc - m) : 0.f;
#pragma unroll
        for (int off = 32; off; off >>= 1) ex += __shfl_xor(ex, off);
        if (act) out[(size_t)i * 40 + lane] = acc - m - logf(ex);
    }
}

// ---------------------------------------------------------------------------
extern "C" void kernel_launch(void* const* d_in, const int* in_sizes, int n_in,
                              void* d_out, int out_size, void* d_ws, size_t ws_size,
                              hipStream_t stream) {
    const float* x   = (const float*)d_in[0];
    const unsigned* ei = (const unsigned*)d_in[1];
    const float* ew  = (const float*)d_in[2];
    const float* W0  = (const float*)d_in[3];
    const float* b0  = (const float*)d_in[4];
    const float* g0  = (const float*)d_in[5];
    const float* be0 = (const float*)d_in[6];
    const float* W1  = (const float*)d_in[7];
    const float* b1  = (const float*)d_in[8];
    const float* g1  = (const float*)d_in[9];
    const float* be1 = (const float*)d_in[10];
    const float* W2  = (const float*)d_in[11];
    const float* b2  = (const float*)d_in[12];

    const int N = in_sizes[0] / 128;
    const int E = in_sizes[2];
    if (N <= 0 || E <= 0) return;

    // ---- workspace carve-up (all 512B-aligned) ----
    char* ws = (char*)d_ws;
    size_t off = 0;
    auto carve = [&](size_t bytes) {
        char* p = ws + off;
        off += (bytes + 511) & ~((size_t)511);
        return p;
    };
    float* bufA   = (float*)carve((size_t)N * 128 * 4);
    float* bufB   = (float*)carve((size_t)N * 128 * 4);
    int*   srcs   = (int*)carve((size_t)E * 4);
    float* coefs  = (float*)carve((size_t)E * 4);
    int*   rowptr = (int*)carve((size_t)(N + 1) * 4);
    int*   fill   = (int*)carve((size_t)N * 4);
    int*   counts = (int*)carve((size_t)N * 4);
    float* degw   = (float*)carve((size_t)N * 4);
    float* dinv   = (float*)carve((size_t)N * 4);
    int*   bsums  = (int*)carve(1024 * 4);
    float* bn     = (float*)carve(512 * 4);  // sum[128] sq[128] scale[128] shift[128]
    int*   flag   = (int*)carve(64);

    // ---- zero-init accumulators (ws is poisoned 0xAA before every launch) ----
    hipMemsetAsync(degw, 0, (size_t)N * 4, stream);
    hipMemsetAsync(counts, 0, (size_t)N * 4, stream);
    hipMemsetAsync(flag, 0, 4, stream);

    // ---- edge dtype detect + CSR build ----
    int nsample = E < 4096 ? E : 4096;
    k_detect<<<(nsample + 255) / 256, 256, 0, stream>>>(ei, nsample, flag);
    k_deg<<<(E + 255) / 256, 256, 0, stream>>>(ei, ew, degw, counts, flag, E);
    const int NB = (N + 511) / 512;
    k_scan_a<<<NB, 512, 0, stream>>>(counts, bsums, N);
    k_scan_b<<<1, 256, 0, stream>>>(bsums, NB);
    k_scan_c<<<NB, 512, 0, stream>>>(counts, bsums, rowptr, fill, degw, dinv, N, E);
    k_scatter<<<(E + 255) / 256, 256, 0, stream>>>(ei, ew, dinv, fill, srcs, coefs, flag, E);

    const int gemm_grid = 768;
    const int agg_grid = (N + 63) / 64;

    // ---- layer 0: GEMM -> agg(+bias,+BN stats) -> BN finalize ----
    k_gemm<128, 64, false><<<gemm_grid, 256, 0, stream>>>(x, W0, nullptr, nullptr, bufA, N);
    hipMemsetAsync(bn, 0, 1024, stream);
    k_agg128<<<agg_grid, 128, 0, stream>>>(bufA, rowptr, srcs, coefs, dinv, b0, bufB, bn, bn + 128, N);
    k_bnfin<<<1, 128, 0, stream>>>(bn, bn + 128, g0, be0, bn + 256, bn + 384, N);

    // ---- layer 1 ----
    k_gemm<128, 64, true><<<gemm_grid, 256, 0, stream>>>(bufB, W1, bn + 256, bn + 384, bufA, N);
    hipMemsetAsync(bn, 0, 1024, stream);
    k_agg128<<<agg_grid, 128, 0, stream>>>(bufA, rowptr, srcs, coefs, dinv, b1, bufB, bn, bn + 128, N);
    k_bnfin<<<1, 128, 0, stream>>>(bn, bn + 128, g1, be1, bn + 256, bn + 384, N);

    // ---- layer 2: GEMM(40) -> agg40 + log_softmax -> d_out ----
    k_gemm<40, 128, true><<<gemm_grid, 256, 0, stream>>>(bufB, W2, bn + 256, bn + 384, bufA, N);
    k_agg40<<<4096, 256, 0, stream>>>(bufA, rowptr, srcs, coefs, dinv, b2, (float*)d_out, N);
}